// Round 12
// baseline (515.275 us; speedup 1.0000x reference)
//
#include <hip/hip_runtime.h>

#define B_SZ 64
#define T_LEN 2048
#define NIN 257
#define HID 32
#define G4 128
#define NOUT 10

#define TBT 128         // rows per xproj tile
#define PAD 34
#define CH 8
#define NSCAN 64
#define NGEMMP 1024     // one tile per producer block (r7-proven fast drain)
#define NTILE 1024      // 16 t-tiles * 64 batches
#define TPB 16          // t-tiles per batch

#define SC_SIG  -1.44269504f   // -log2(e): sigmoid via exp2
#define SC_TANH -2.88539008f   // -2*log2(e): tanh via 2*sig(2x)-1, fold into scale

typedef int v2i __attribute__((ext_vector_type(2)));
typedef unsigned long long u64;

// f16-pair GEMV ops (v_pk_*_f16; hp broadcast from SGPR)
#define PKMUL16(d, w, hpk) \
  asm("v_pk_mul_f16 %0, %1, %2" : "=v"(d) : "v"(w), "s"(hpk))
#define PKFMA16(acc, w, hpk) \
  asm("v_pk_fma_f16 %0, %1, %2, %0" : "+v"(acc) : "v"(w), "s"(hpk))
#define PKADD16(d, a, b) \
  asm("v_pk_add_f16 %0, %1, %2" : "=v"(d) : "v"(a), "v"(b))
// acc(f32) += u.lo + u.hi  via dot2 with (1.0h,1.0h): folds h-sum + exact-f32 x
#define DOT2ONES(acc, u, ones) \
  asm("v_dot2_f32_f16 %0, %1, %2, %0" : "+v"(acc) : "v"(u), "s"(ones))

// pack two f32 -> f16 pair (lo = a, hi = b), round-toward-zero
#define PKF16(dst, a, b) \
  asm("v_cvt_pkrtz_f16_f32 %0, %1, %2" : "=v"(dst) : "v"(a), "v"(b))

// ---- GEMM tile body: writes xproj rows [bt0, bt0+128) ----
// Output layout: per row t, 64 float2 pairs: pair[c] = (col c, col c+64),
// pre-scaled by the activation exp2 constant for that column group.
__device__ __forceinline__ void gemm_tile(
    const float* __restrict__ A, const float* __restrict__ W,
    const float* __restrict__ b_ih, const float* __restrict__ b_hh,
    float* __restrict__ C, int bt0, float* sA, float* sB)
{
  const int tid = threadIdx.x;
  const int gt = tid & 15;
  const int btt = tid >> 4;
  float acc[8][8];
#pragma unroll
  for (int i = 0; i < 8; ++i)
#pragma unroll
    for (int j = 0; j < 8; ++j) acc[i][j] = 0.f;

  for (int kc = 0; kc < 8; ++kc) {
    const int k0 = kc * 32;
    __syncthreads();
#pragma unroll
    for (int i = 0; i < 16; ++i) {
      int s = i * 256 + tid;
      int r = s >> 5, cc = s & 31;
      sA[r * PAD + cc] = A[(size_t)(bt0 + r) * NIN + k0 + cc];
      sB[r * PAD + cc] = W[(size_t)r * NIN + k0 + cc];
    }
    __syncthreads();
#pragma unroll
    for (int k2 = 0; k2 < 16; ++k2) {
      float2 a2[8], b2[8];
#pragma unroll
      for (int i = 0; i < 8; ++i)
        a2[i] = *(const float2*)&sA[(btt + 16 * i) * PAD + 2 * k2];
#pragma unroll
      for (int j = 0; j < 8; ++j)
        b2[j] = *(const float2*)&sB[(gt + 16 * j) * PAD + 2 * k2];
#pragma unroll
      for (int i = 0; i < 8; ++i)
#pragma unroll
        for (int j = 0; j < 8; ++j) {
          acc[i][j] = fmaf(a2[i].x, b2[j].x, acc[i][j]);
          acc[i][j] = fmaf(a2[i].y, b2[j].y, acc[i][j]);
        }
    }
  }
  { // k = 256 tail
    float a[8], bb[8];
#pragma unroll
    for (int i = 0; i < 8; ++i) a[i] = A[(size_t)(bt0 + btt + 16 * i) * NIN + 256];
#pragma unroll
    for (int j = 0; j < 8; ++j) bb[j] = W[(size_t)(gt + 16 * j) * NIN + 256];
#pragma unroll
    for (int i = 0; i < 8; ++i)
#pragma unroll
      for (int j = 0; j < 8; ++j) acc[i][j] += a[i] * bb[j];
  }
  float bias[8], sc[8];
  int off[8];
#pragma unroll
  for (int j = 0; j < 8; ++j) {
    const int col = gt + 16 * j;
    bias[j] = b_ih[col] + b_hh[col];
    sc[j] = ((col >> 5) == 2) ? SC_TANH : SC_SIG;   // g-columns get tanh fold
    off[j] = ((col & 63) << 1) + (col >> 6);        // paired layout
  }
#pragma unroll
  for (int i = 0; i < 8; ++i) {
    size_t row = (size_t)(bt0 + btt + 16 * i) * G4;
#pragma unroll
    for (int j = 0; j < 8; ++j) C[row + off[j]] = (acc[i][j] + bias[j]) * sc[j];
  }
}

// ---- Fused kernel: blocks [0,64) scan, [64,64+NGEMMP) producer ----
__global__ __launch_bounds__(256) void fused(
    const float* __restrict__ A,      // specs
    const float* __restrict__ W,      // W_ih
    const float* __restrict__ b_ih,
    const float* __restrict__ b_hh,
    const float* __restrict__ W_hh,
    const float* __restrict__ W_out,
    const float* __restrict__ b_out,
    float* __restrict__ out,
    float* __restrict__ xproj,
    int* __restrict__ flags,
    int nowait)
{
  __shared__ float sA[TBT * PAD];
  __shared__ float sB[G4 * PAD];
  const int bid = blockIdx.x;

  if (bid >= NSCAN) {
    // -------- producer: one tile per block, tile-major (ti*64 + b) --------
    // Priority ladder: ti=0 tier runs at prio 2 (starves co-resident prio-0
    // producers on its CU -> near-solo rate), ti=1 at prio 1, rest at 0.
    // (s_setprio requires an immediate -> wave-uniform constant branches.)
    const int p = bid - NSCAN;
    const int ptier = p >> 6;          // == ti for NGEMMP=1024
    if (ptier == 0) {
      __builtin_amdgcn_s_setprio(2);
    } else if (ptier == 1) {
      __builtin_amdgcn_s_setprio(1);
    } else {
      __builtin_amdgcn_s_setprio(0);
    }
    for (int idx = p; idx < NTILE; idx += NGEMMP) {
      const int ti = idx >> 6, bb = idx & 63;
      const int bt0 = bb * T_LEN + ti * TBT;
      gemm_tile(A, W, b_ih, b_hh, xproj, bt0, sA, sB);
      __threadfence();
      __syncthreads();
      if (threadIdx.x == 0)
        __hip_atomic_store(&flags[idx], 1, __ATOMIC_RELEASE, __HIP_MEMORY_SCOPE_AGENT);
    }
    return;
  }

  // -------- consumer: LSTM scan, one wave per batch element --------
  if (threadIdx.x >= 64) return;
  __builtin_amdgcn_s_setprio(3);
  const int b = bid;
  const int l = threadIdx.x;

  // f16-pair packed recurrent weights, PRE-SCALED by activation exp2 consts:
  // wA[k] = f16(W_hh[l][2k]*sA, W_hh[l][2k+1]*sA), sA = SC_SIG (i/f rows)
  // wB[k] = same for row l+64 with SC_TANH (g rows, l<32) / SC_SIG (o rows)
  const float wsB = (l < HID) ? SC_TANH : SC_SIG;
  unsigned wA[16], wB[16];
#pragma unroll
  for (int j = 0; j < 16; j += 2) {
    float4 v0 = *(const float4*)&W_hh[l * HID + 2 * j];
    PKF16(wA[j],     v0.x * SC_SIG, v0.y * SC_SIG);
    PKF16(wA[j + 1], v0.z * SC_SIG, v0.w * SC_SIG);
    float4 v1 = *(const float4*)&W_hh[(l + 64) * HID + 2 * j];
    PKF16(wB[j],     v1.x * wsB, v1.y * wsB);
    PKF16(wB[j + 1], v1.z * wsB, v1.w * wsB);
  }
  const unsigned sONES = 0x3C003C00u;  // (1.0h, 1.0h) for horizontal-sum dot

  float c = 0.f, h = 0.f;          // c holds SC_TANH * c_true (pre-scaled)
  unsigned hp[16];                 // h broadcast as f16 pairs (SGPRs)
#pragma unroll
  for (int k = 0; k < 16; ++k) hp[k] = 0u;

  const float2* xb2 = (const float2*)(xproj + (size_t)b * T_LEN * G4);

  auto step = [&](float xa, float xg) {
    // f16-rate GEMV: 4 independent pk chains of depth 4 per gate (mul heads,
    // no zero-init), f16x2 partial sums; horizontal fold + exact-f32 x via
    // one dot2-with-ones per gate.
    unsigned uA0, uA1, uA2, uA3, uB0, uB1, uB2, uB3;
    PKMUL16(uA0, wA[0],  hp[0]);
    PKMUL16(uA1, wA[4],  hp[4]);
    PKMUL16(uA2, wA[8],  hp[8]);
    PKMUL16(uA3, wA[12], hp[12]);
    PKMUL16(uB0, wB[0],  hp[0]);
    PKMUL16(uB1, wB[4],  hp[4]);
    PKMUL16(uB2, wB[8],  hp[8]);
    PKMUL16(uB3, wB[12], hp[12]);
#pragma unroll
    for (int j = 1; j < 4; ++j) {
      PKFMA16(uA0, wA[j],      hp[j]);
      PKFMA16(uA1, wA[4 + j],  hp[4 + j]);
      PKFMA16(uA2, wA[8 + j],  hp[8 + j]);
      PKFMA16(uA3, wA[12 + j], hp[12 + j]);
      PKFMA16(uB0, wB[j],      hp[j]);
      PKFMA16(uB1, wB[4 + j],  hp[4 + j]);
      PKFMA16(uB2, wB[8 + j],  hp[8 + j]);
      PKFMA16(uB3, wB[12 + j], hp[12 + j]);
    }
    unsigned rA0, rA1, rA, rB0, rB1, rB;
    PKADD16(rA0, uA0, uA1); PKADD16(rA1, uA2, uA3); PKADD16(rA, rA0, rA1);
    PKADD16(rB0, uB0, uB1); PKADD16(rB1, uB2, uB3); PKADD16(rB, rB0, rB1);
    float accA = xa, accB = xg;        // exact-f32 x path
    DOT2ONES(accA, rA, sONES);         // accA = xa + sum(rA)   (pre-scaled i/f)
    DOT2ONES(accB, rB, sONES);         // accB = xg + sum(rB)   (pre-scaled 2g/o)
    float actA = __builtin_amdgcn_rcpf(1.f + __builtin_amdgcn_exp2f(accA));
    float sB2  = __builtin_amdgcn_rcpf(1.f + __builtin_amdgcn_exp2f(accB));
    // lanes<32: prod = SC_TANH * i * tanh(g) = (2*SC_TANH*i) * (sig2g - 0.5)
    float m1 = actA * (2.f * SC_TANH);         // off critical path
    float sh = sB2 - 0.5f;
    float prod = m1 * sh;
    // measured semantics: swap(vdst=0, src=prod) -> dst_new[32+k] = prod[k]
    v2i sw = __builtin_amdgcn_permlane32_swap(0, __float_as_int(prod), false, false);
    float pr = __int_as_float(sw[0]);
    c = fmaf(actA, c, pr);                     // lanes>=32: SC_TANH*(f*c + i*g)
    float t  = __builtin_amdgcn_rcpf(1.f + __builtin_amdgcn_exp2f(c));
    float s2 = sB2 + sB2;                      // off critical path (o = sB2)
    h = fmaf(s2, t, -sB2);                     // lanes>=32: h = o*tanh(c_true)
    // broadcast h as f16 pairs: neighbor via quad-perm DPP, pack, 16 readlanes
    int hn = __builtin_amdgcn_mov_dpp(__float_as_int(h), 0xF5, 0xF, 0xF, false);
    int pk;
    PKF16(pk, h, __int_as_float(hn));          // lane 32+2k: (h[2k], h[2k+1])
#pragma unroll
    for (int k = 0; k < 16; ++k)
      hp[k] = (unsigned)__builtin_amdgcn_readlane(pk, 32 + 2 * k);
  };

  float2 X0[CH], X1[CH];
#define LOADC2(X, P) do { _Pragma("unroll") \
  for (int i = 0; i < CH; ++i) X[i] = (P)[i * 64]; } while (0)
#define STEPS(X) do { _Pragma("unroll") \
  for (int i = 0; i < CH; ++i) step(X[i].x, X[i].y); } while (0)

  for (int ti = 0; ti < TPB; ++ti) {
    if (!nowait) {
      while (__hip_atomic_load(&flags[ti * 64 + b], __ATOMIC_ACQUIRE,
                               __HIP_MEMORY_SCOPE_AGENT) == 0)
        __builtin_amdgcn_s_sleep(2);
    }
    const float2* xt = xb2 + (size_t)ti * TBT * 64 + l;
    LOADC2(X0, xt);
#pragma unroll 1
    for (int ch = 0; ch < TBT / CH; ch += 2) {
      const float2* s1 = xt + (size_t)(ch + 1) * CH * 64;
      LOADC2(X1, s1);
      STEPS(X0);
      if (ch + 2 < TBT / CH) {
        const float2* s2 = xt + (size_t)(ch + 2) * CH * 64;
        LOADC2(X0, s2);
      }
      STEPS(X1);
    }
  }

  // head: logits = relu(h) @ W_out.T + b_out ; log_softmax  (shuffle-only)
  // h here is the exact fp32 lane value (f16 was only the broadcast copy)
  float hf[HID];
#pragma unroll
  for (int k = 0; k < HID; ++k)
    hf[k] = __int_as_float(__builtin_amdgcn_readlane(__float_as_int(h), 32 + k));
  float logit = 0.f;
  if (l < NOUT) {
    logit = b_out[l];
#pragma unroll
    for (int j = 0; j < HID; ++j) logit += fmaxf(hf[j], 0.f) * W_out[l * HID + j];
  }
  float m = -1e30f;
#pragma unroll
  for (int n = 0; n < NOUT; ++n) m = fmaxf(m, __shfl(logit, n));
  float s = 0.f;
#pragma unroll
  for (int n = 0; n < NOUT; ++n)
    s += __builtin_amdgcn_exp2f(1.44269504089f * (__shfl(logit, n) - m));
  if (l < NOUT)
    out[b * NOUT + l] = logit - m - 0.69314718056f * __builtin_amdgcn_logf(s);
}

// ---- fallback standalone GEMM (serial path if ws too small for flags) ----
__global__ __launch_bounds__(256) void xproj_gemm(
    const float* __restrict__ A, const float* __restrict__ W,
    const float* __restrict__ b_ih, const float* __restrict__ b_hh,
    float* __restrict__ C)
{
  __shared__ float sA[TBT * PAD];
  __shared__ float sB[G4 * PAD];
  const int idx = blockIdx.x;
  const int ti = idx >> 6, bb = idx & 63;
  gemm_tile(A, W, b_ih, b_hh, C, bb * T_LEN + ti * TBT, sA, sB);
}

extern "C" void kernel_launch(void* const* d_in, const int* in_sizes, int n_in,
                              void* d_out, int out_size, void* d_ws, size_t ws_size,
                              hipStream_t stream) {
  const float* specs = (const float*)d_in[0];
  const float* W_ih  = (const float*)d_in[1];
  const float* W_hh  = (const float*)d_in[2];
  const float* b_ih  = (const float*)d_in[3];
  const float* b_hh  = (const float*)d_in[4];
  const float* W_out = (const float*)d_in[5];
  const float* b_out = (const float*)d_in[6];
  float* outp  = (float*)d_out;
  float* xproj = (float*)d_ws;                       // 64 MB
  const size_t xbytes = (size_t)B_SZ * T_LEN * G4 * 4;

  if (ws_size >= xbytes + NTILE * sizeof(int)) {
    int* flags = (int*)((char*)d_ws + xbytes);
    (void)hipMemsetAsync(flags, 0, NTILE * sizeof(int), stream);
    fused<<<NSCAN + NGEMMP, 256, 0, stream>>>(specs, W_ih, b_ih, b_hh, W_hh,
                                              W_out, b_out, outp, xproj, flags, 0);
  } else {
    xproj_gemm<<<NTILE, 256, 0, stream>>>(specs, W_ih, b_ih, b_hh, xproj);
    fused<<<NSCAN, 256, 0, stream>>>(specs, W_ih, b_ih, b_hh, W_hh,
                                     W_out, b_out, outp, xproj, (int*)xproj /*unused*/, 1);
  }
}